// Round 8
// baseline (196.360 us; speedup 1.0000x reference)
//
#include <hip/hip_runtime.h>
#include <math.h>

#define N_TOK 65536
#define DIM   512
#define HID   102
#define KTOK  64
#define NTILE 4096          // 16-token tiles (one per wave)
#define LN_EPS 1e-5f

typedef __attribute__((ext_vector_type(8))) short short8;
typedef __attribute__((ext_vector_type(4))) float f32x4;

// ws layout (float offsets)
#define WS_LOGITS 0u
#define WS_PART   4194304u                 // 128*64*512
#define WS_PM     (WS_PART + 4194304u)     // 4096*64
#define WS_PS     (WS_PM + 262144u)        // 4096*64
#define WS_W1F    (WS_PS + 262144u)        // 65536 ushort (chunk-packed frags)
#define WS_W2F    (WS_W1F + 32768u)        // 8192 ushort (packed frags)
#define WS_B1P    (WS_W2F + 4096u)
#define WS_SMAX   (WS_B1P + 128u)
#define WS_SINV   (WS_SMAX + 64u)

__device__ __forceinline__ unsigned short f2bf(float f) {
    unsigned int u = __float_as_uint(f);
    unsigned int r = (u + 0x7fffu + ((u >> 16) & 1u)) >> 16;
    return (unsigned short)r;
}

__device__ __forceinline__ void gload_lds16(const void* g, void* l) {
    __builtin_amdgcn_global_load_lds(
        (const __attribute__((address_space(1))) unsigned int*)g,
        (__attribute__((address_space(3))) unsigned int*)l, 16, 0, 0);
}

// ---------------- prep: weights packed in MFMA-fragment order ----------------
// W1f chunk-packed: W1f[kc*4096 + jj*512 + lane*8 + e] = W1[d][j],
//   j = jj*16 + (lane&15), d = kc*32 + (lane>>4)*8 + e   (kc=0..15, jj=0..7)
// W2f[((N*4+kc)*64+lane)*8+e] = W2[j][k], k=N*16+(lane&15), j=kc*32+(lane>>4)*8+e
__global__ __launch_bounds__(256) void prep_k(const float* __restrict__ W1,
                                              const float* __restrict__ b1,
                                              const float* __restrict__ W2,
                                              unsigned short* __restrict__ W1f,
                                              unsigned short* __restrict__ W2f,
                                              float* __restrict__ b1p) {
    const int idx = blockIdx.x * 256 + threadIdx.x;   // 0..65535
    {
        const int e = idx & 7, lane = (idx >> 3) & 63;
        const int jj = (idx >> 9) & 7, kc = (idx >> 12) & 15;
        const int j = jj * 16 + (lane & 15);
        const int d = kc * 32 + (lane >> 4) * 8 + e;
        W1f[idx] = (j < HID) ? f2bf(W1[d * HID + j]) : (unsigned short)0;
    }
    if (idx < 8192) {
        const int e = idx & 7, lane = (idx >> 3) & 63;
        const int kc = (idx >> 9) & 3, N = (idx >> 11) & 3;
        const int j = kc * 32 + (lane >> 4) * 8 + e;
        const int k = N * 16 + (lane & 15);
        W2f[idx] = (j < HID) ? f2bf(W2[j * KTOK + k]) : (unsigned short)0;
    }
    if (idx < 128) b1p[idx] = (idx < HID) ? b1[idx] : 0.0f;
}

// ------- scorer: 64 tokens/block (16/wave), LDS-shared B,
//         triple-buffered counted-vmcnt fc1 (1 barrier/K-step) -------
__global__ __launch_bounds__(256) void scorer_k(const float* __restrict__ x,
                                                const float* __restrict__ gamma,
                                                const float* __restrict__ beta,
                                                const unsigned short* __restrict__ W1f,
                                                const unsigned short* __restrict__ W2f,
                                                const float* __restrict__ b1p,
                                                const float* __restrict__ b2,
                                                const float* __restrict__ scale,
                                                float* __restrict__ logits,
                                                float* __restrict__ pm,
                                                float* __restrict__ psum) {
    __shared__ char bsm[3][8192];       // B triple buffer (8 KB K-chunk each)
    __shared__ char hsm[4][4096];       // per-wave h bounce
    const int tid = threadIdx.x;
    const int lane = tid & 63;
    const int w = tid >> 6;
    const int l15 = lane & 15;
    const int hi = lane >> 4;
    const int tile = blockIdx.x * 4 + w;
    const int wt0 = tile * 16;
    char* hb = &hsm[w][0];

    // stage fc1 chunk 0 ASAP (hides under both LN passes)
    {
        const unsigned short* s0 = W1f + w * 1024 + lane * 8;
        gload_lds16(s0, &bsm[0][w * 2048]);
        gload_lds16(s0 + 512, &bsm[0][w * 2048 + 1024]);
    }

    // ---- LN pass 1: full-row sums, 2-shfl reduce (4 lanes share a row) ----
    const float* xrow = x + (size_t)(wt0 + l15) * DIM + hi * 8;
    float s = 0.0f, ss = 0.0f;
    #pragma unroll
    for (int kc = 0; kc < 16; ++kc) {
        const f32x4 a = *(const f32x4*)(xrow + kc * 32);
        const f32x4 b = *(const f32x4*)(xrow + kc * 32 + 4);
        s += a.x + a.y + a.z + a.w + b.x + b.y + b.z + b.w;
        ss += a.x * a.x + a.y * a.y + a.z * a.z + a.w * a.w +
              b.x * b.x + b.y * b.y + b.z * b.z + b.w * b.w;
        if ((kc & 3) == 3) __builtin_amdgcn_sched_barrier(0);
    }
    s += __shfl_xor(s, 16); ss += __shfl_xor(ss, 16);
    s += __shfl_xor(s, 32); ss += __shfl_xor(ss, 32);
    const float mu = s * (1.0f / 512.0f);
    const float inv = rsqrtf(ss * (1.0f / 512.0f) - mu * mu + LN_EPS);

    asm volatile("" : "+v"(xrow));   // launder: force reload (stop CSE->spill)

    // ---- LN pass 2: normalize+pack straight into A-fragments ----
    short8 nx[16];
    #pragma unroll
    for (int kc = 0; kc < 16; ++kc) {
        const f32x4 a = *(const f32x4*)(xrow + kc * 32);
        const f32x4 b = *(const f32x4*)(xrow + kc * 32 + 4);
        const f32x4 g0 = *(const f32x4*)(gamma + kc * 32 + hi * 8);
        const f32x4 g1 = *(const f32x4*)(gamma + kc * 32 + hi * 8 + 4);
        const f32x4 e0 = *(const f32x4*)(beta + kc * 32 + hi * 8);
        const f32x4 e1 = *(const f32x4*)(beta + kc * 32 + hi * 8 + 4);
        short8 v;
        v[0] = (short)f2bf((a.x - mu) * inv * g0.x + e0.x);
        v[1] = (short)f2bf((a.y - mu) * inv * g0.y + e0.y);
        v[2] = (short)f2bf((a.z - mu) * inv * g0.z + e0.z);
        v[3] = (short)f2bf((a.w - mu) * inv * g0.w + e0.w);
        v[4] = (short)f2bf((b.x - mu) * inv * g1.x + e1.x);
        v[5] = (short)f2bf((b.y - mu) * inv * g1.y + e1.y);
        v[6] = (short)f2bf((b.z - mu) * inv * g1.z + e1.z);
        v[7] = (short)f2bf((b.w - mu) * inv * g1.w + e1.w);
        nx[kc] = v;
        if ((kc & 3) == 3) __builtin_amdgcn_sched_barrier(0);
    }

    // ---- fc1: 16 K-steps, triple-buffered, 1 barrier/step ----
    // step kc: stage(kc+1)->buf[(kc+1)%3]; vmcnt(2) [own stage(kc) landed];
    //          barrier [all waves' stage(kc) landed]; 8 MFMA from buf[kc%3].
    // Reuse safety: buf[(kc+1)%3] was last read at step kc-2; those reads
    // completed before barrier(kc-1) (MFMA issue forces the ds_read wait).
    f32x4 acc[8] = {};
    #pragma unroll
    for (int kc = 0; kc < 16; ++kc) {
        if (kc < 15) {   // stage next chunk
            const unsigned short* sn = W1f + (kc + 1) * 4096 + w * 1024 + lane * 8;
            gload_lds16(sn, &bsm[(kc + 1) % 3][w * 2048]);
            gload_lds16(sn + 512, &bsm[(kc + 1) % 3][w * 2048 + 1024]);
            asm volatile("s_waitcnt vmcnt(2)" ::: "memory");
        } else {
            asm volatile("s_waitcnt vmcnt(0)" ::: "memory");
        }
        __builtin_amdgcn_sched_barrier(0);
        __builtin_amdgcn_s_barrier();      // all waves' stage(kc) landed
        const char* bb = &bsm[kc % 3][lane * 16];
        __builtin_amdgcn_s_setprio(1);
        #pragma unroll
        for (int jj = 0; jj < 8; ++jj) {
            const short8 bf = *(const short8*)(bb + jj * 1024);
            acc[jj] = __builtin_amdgcn_mfma_f32_16x16x32_bf16(nx[kc], bf, acc[jj], 0, 0, 0);
        }
        __builtin_amdgcn_s_setprio(0);
    }

    // ---- bias + GELU -> wave-private LDS (swizzled bf16) ----
    #pragma unroll
    for (int jj = 0; jj < 8; ++jj) {
        const int col = jj * 16 + l15;
        const float bias = b1p[col];
        #pragma unroll
        for (int reg = 0; reg < 4; ++reg) {
            const int t = 4 * hi + reg;
            const float tt = acc[jj][reg] + bias;
            const float g = 0.5f * tt * (1.0f + erff(tt * 0.70710678118f));
            *(unsigned short*)(hb + t * 256 + ((col * 2) ^ ((t & 7) << 4))) = f2bf(g);
        }
    }
    asm volatile("s_waitcnt lgkmcnt(0)" ::: "memory");
    __builtin_amdgcn_sched_barrier(0);

    // ---- fc2: 16 tokens x 64 k (per-wave, W2f from L2) ----
    f32x4 acc2[4] = {};
    {
        const unsigned short* w2 = W2f + lane * 8;
        #pragma unroll
        for (int kc = 0; kc < 4; ++kc) {
            const short8 a2 = *(const short8*)(hb + l15 * 256 +
                                               ((kc * 64 + hi * 16) ^ ((l15 & 7) << 4)));
            __builtin_amdgcn_s_setprio(1);
            #pragma unroll
            for (int nt = 0; nt < 4; ++nt) {
                const short8 bfr = *(const short8*)(w2 + (size_t)(nt * 4 + kc) * 512);
                acc2[nt] = __builtin_amdgcn_mfma_f32_16x16x32_bf16(a2, bfr, acc2[nt], 0, 0, 0);
            }
            __builtin_amdgcn_s_setprio(0);
        }
    }

    // ---- logits store (16B/lane contiguous) + per-tile softmax partials ----
    const float sc = scale[0];
    #pragma unroll
    for (int nt = 0; nt < 4; ++nt) {
        const int k = nt * 16 + l15;
        const float bb = b2[k];
        f32x4 lv;
        lv.x = (acc2[nt][0] + bb) * sc;
        lv.y = (acc2[nt][1] + bb) * sc;
        lv.z = (acc2[nt][2] + bb) * sc;
        lv.w = (acc2[nt][3] + bb) * sc;
        *(f32x4*)(logits + (size_t)k * N_TOK + wt0 + hi * 4) = lv;
        float m4 = fmaxf(fmaxf(lv.x, lv.y), fmaxf(lv.z, lv.w));
        float s4 = __expf(lv.x - m4) + __expf(lv.y - m4) +
                   __expf(lv.z - m4) + __expf(lv.w - m4);
        #pragma unroll
        for (int o = 16; o <= 32; o <<= 1) {
            const float om = __shfl_xor(m4, o);
            const float os = __shfl_xor(s4, o);
            const float nm = fmaxf(m4, om);
            s4 = s4 * __expf(m4 - nm) + os * __expf(om - nm);
            m4 = nm;
        }
        if (hi == 0) {
            pm[tile * 64 + k] = m4;
            psum[tile * 64 + k] = s4;
        }
    }
}

// ---------------- stats: combine per-tile partials ----------------
__global__ __launch_bounds__(256) void stats_k(const float* __restrict__ pm,
                                               const float* __restrict__ psum,
                                               float* __restrict__ smax,
                                               float* __restrict__ sinv) {
    const int k = blockIdx.x;
    const int tid = threadIdx.x;
    __shared__ float rm[4], rs[4];
    float m = -1e30f, s = 0.0f;
    for (int b = tid; b < NTILE; b += 256) {
        const float pmv = pm[b * 64 + k];
        const float psv = psum[b * 64 + k];
        const float nm = fmaxf(m, pmv);
        s = s * __expf(m - nm) + psv * __expf(pmv - nm);
        m = nm;
    }
    #pragma unroll
    for (int o = 32; o >= 1; o >>= 1) {
        const float om = __shfl_xor(m, o);
        const float os = __shfl_xor(s, o);
        const float nm = fmaxf(m, om);
        s = s * __expf(m - nm) + os * __expf(om - nm);
        m = nm;
    }
    if ((tid & 63) == 0) { rm[tid >> 6] = m; rs[tid >> 6] = s; }
    __syncthreads();
    if (tid == 0) {
        float fm = rm[0], fs = rs[0];
        for (int i = 1; i < 4; ++i) {
            const float nm = fmaxf(fm, rm[i]);
            fs = fs * __expf(fm - nm) + rs[i] * __expf(rm[i] - nm);
            fm = nm;
        }
        smax[k] = fm;
        sinv[k] = 1.0f / fs;
    }
}

// ---------------- agg: partial[tb][k][d], 512 tokens/block (R3-proven) ----------------
__global__ __launch_bounds__(512, 4) void agg_k(const float* __restrict__ x,
                                                const float* __restrict__ logits,
                                                const float* __restrict__ smax,
                                                const float* __restrict__ sinv,
                                                float* __restrict__ part) {
    __shared__ float ps[64][65];
    const int tid = threadIdx.x;
    const int dg = blockIdx.y;
    const int tb = blockIdx.x;
    const int kq = tid >> 5;            // 0..15 -> k = kq*4..+4
    const int dt = tid & 31;
    const int dbase = dg * 128 + dt * 4;
    const int n_start = tb * 512;
    const int sk = tid >> 3;            // staging: k row 0..63
    const int np = (tid & 7) * 8;       // staging: 8 tokens
    const float mk = smax[sk];
    const float ik = sinv[sk];
    float acc[4][4] = {};

    for (int c = 0; c < 8; ++c) {
        const int n0 = n_start + c * 64;
        const f32x4 va = *(const f32x4*)&logits[(size_t)sk * N_TOK + n0 + np];
        const f32x4 vb = *(const f32x4*)&logits[(size_t)sk * N_TOK + n0 + np + 4];
        __syncthreads();
        ps[sk][np + 0] = __expf(va.x - mk) * ik;
        ps[sk][np + 1] = __expf(va.y - mk) * ik;
        ps[sk][np + 2] = __expf(va.z - mk) * ik;
        ps[sk][np + 3] = __expf(va.w - mk) * ik;
        ps[sk][np + 4] = __expf(vb.x - mk) * ik;
        ps[sk][np + 5] = __expf(vb.y - mk) * ik;
        ps[sk][np + 6] = __expf(vb.z - mk) * ik;
        ps[sk][np + 7] = __expf(vb.w - mk) * ik;
        __syncthreads();
        #pragma unroll 4
        for (int n = 0; n < 64; ++n) {
            const f32x4 xv = *(const f32x4*)&x[(size_t)(n0 + n) * DIM + dbase];
            #pragma unroll
            for (int i = 0; i < 4; ++i) {
                const float p = ps[kq * 4 + i][n];
                acc[i][0] = fmaf(p, xv.x, acc[i][0]);
                acc[i][1] = fmaf(p, xv.y, acc[i][1]);
                acc[i][2] = fmaf(p, xv.z, acc[i][2]);
                acc[i][3] = fmaf(p, xv.w, acc[i][3]);
            }
        }
    }
    #pragma unroll
    for (int i = 0; i < 4; ++i) {
        const int k = kq * 4 + i;
        f32x4 v;
        v.x = acc[i][0]; v.y = acc[i][1]; v.z = acc[i][2]; v.w = acc[i][3];
        *(f32x4*)&part[((size_t)tb * 64 + k) * 512 + dbase] = v;
    }
}

// ---------------- reduce: out[k][d] = sum_tb part[tb][k][d] ----------------
__global__ __launch_bounds__(256) void reduce_k(const float* __restrict__ part,
                                                float* __restrict__ out) {
    const int idx = blockIdx.x * 256 + threadIdx.x;  // 0..32767
    const int k = idx >> 9, d = idx & 511;
    float s = 0.0f;
    for (int tb = 0; tb < 128; ++tb) s += part[((size_t)tb * 64 + k) * 512 + d];
    out[idx] = s;
}

extern "C" void kernel_launch(void* const* d_in, const int* in_sizes, int n_in,
                              void* d_out, int out_size, void* d_ws, size_t ws_size,
                              hipStream_t stream) {
    const float* x     = (const float*)d_in[0];
    const float* gamma = (const float*)d_in[1];
    const float* beta  = (const float*)d_in[2];
    const float* W1    = (const float*)d_in[3];
    const float* b1    = (const float*)d_in[4];
    const float* W2    = (const float*)d_in[5];
    const float* b2    = (const float*)d_in[6];
    const float* scale = (const float*)d_in[7];
    float* out = (float*)d_out;
    float* ws  = (float*)d_ws;

    float* logits = ws + WS_LOGITS;
    float* part   = ws + WS_PART;
    float* pm     = ws + WS_PM;
    float* psum   = ws + WS_PS;
    unsigned short* W1f = (unsigned short*)(ws + WS_W1F);
    unsigned short* W2f = (unsigned short*)(ws + WS_W2F);
    float* b1p  = ws + WS_B1P;
    float* smax = ws + WS_SMAX;
    float* sinv = ws + WS_SINV;

    hipLaunchKernelGGL(prep_k, dim3(256), dim3(256), 0, stream,
                       W1, b1, W2, W1f, W2f, b1p);
    hipLaunchKernelGGL(scorer_k, dim3(NTILE / 4), dim3(256), 0, stream,
                       x, gamma, beta, W1f, W2f, b1p, b2, scale, logits, pm, psum);
    hipLaunchKernelGGL(stats_k, dim3(KTOK), dim3(256), 0, stream,
                       pm, psum, smax, sinv);
    hipLaunchKernelGGL(agg_k, dim3(128, 4), dim3(512), 0, stream,
                       x, logits, smax, sinv, part);
    hipLaunchKernelGGL(reduce_k, dim3(128), dim3(256), 0, stream,
                       part, out);
}

// Round 9
// 168.648 us; speedup vs baseline: 1.1643x; 1.1643x over previous
//
#include <hip/hip_runtime.h>
#include <math.h>

#define N_TOK 65536
#define DIM   512
#define HID   102
#define KTOK  64
#define NTILE 4096          // 16-token tiles (one per wave)
#define LN_EPS 1e-5f

typedef __attribute__((ext_vector_type(8))) short short8;
typedef __attribute__((ext_vector_type(4))) float f32x4;

// ws layout (float offsets)
#define WS_LOGITS 0u
#define WS_PART   4194304u                 // 128*64*512
#define WS_PM     (WS_PART + 4194304u)     // 4096*64
#define WS_PS     (WS_PM + 262144u)        // 4096*64
#define WS_W1F    (WS_PS + 262144u)        // 65536 ushort (chunk-packed frags, gamma-folded)
#define WS_W2F    (WS_W1F + 32768u)        // 8192 ushort (packed frags)
#define WS_UB     (WS_W2F + 4096u)         // 128: sum(beta*W1)+b1
#define WS_VV     (WS_UB + 128u)           // 128: sum(gamma*W1)
#define WS_SMAX   (WS_VV + 128u)
#define WS_SINV   (WS_SMAX + 64u)

__device__ __forceinline__ unsigned short f2bf(float f) {
    unsigned int u = __float_as_uint(f);
    unsigned int r = (u + 0x7fffu + ((u >> 16) & 1u)) >> 16;
    return (unsigned short)r;
}

__device__ __forceinline__ void gload_lds16(const void* g, void* l) {
    __builtin_amdgcn_global_load_lds(
        (const __attribute__((address_space(1))) unsigned int*)g,
        (__attribute__((address_space(3))) unsigned int*)l, 16, 0, 0);
}

// ---------------- prep: weights packed in MFMA-fragment order ----------------
// W1f chunk-packed, GAMMA-FOLDED: W1f[kc*4096 + jj*512 + lane*8 + e] =
//   bf16(gamma[d]*W1[d][j]), j=jj*16+(lane&15), d=kc*32+(lane>>4)*8+e
// W2f[((N*4+kc)*64+lane)*8+e] = W2[j][k], k=N*16+(lane&15), j=kc*32+(lane>>4)*8+e
__global__ __launch_bounds__(256) void prep_k(const float* __restrict__ W1,
                                              const float* __restrict__ gamma,
                                              const float* __restrict__ W2,
                                              unsigned short* __restrict__ W1f,
                                              unsigned short* __restrict__ W2f) {
    const int idx = blockIdx.x * 256 + threadIdx.x;   // 0..65535
    {
        const int e = idx & 7, lane = (idx >> 3) & 63;
        const int jj = (idx >> 9) & 7, kc = (idx >> 12) & 15;
        const int j = jj * 16 + (lane & 15);
        const int d = kc * 32 + (lane >> 4) * 8 + e;
        W1f[idx] = (j < HID) ? f2bf(gamma[d] * W1[d * HID + j]) : (unsigned short)0;
    }
    if (idx < 8192) {
        const int e = idx & 7, lane = (idx >> 3) & 63;
        const int kc = (idx >> 9) & 3, N = (idx >> 11) & 3;
        const int j = kc * 32 + (lane >> 4) * 8 + e;
        const int k = N * 16 + (lane & 15);
        W2f[idx] = (j < HID) ? f2bf(W2[j * KTOK + k]) : (unsigned short)0;
    }
}

// ---------------- prep2: ub[j]=sum_d beta*W1 + b1, vv[j]=sum_d gamma*W1 ----------------
__global__ __launch_bounds__(512) void prep2_k(const float* __restrict__ W1,
                                               const float* __restrict__ b1,
                                               const float* __restrict__ gamma,
                                               const float* __restrict__ beta,
                                               float* __restrict__ ub,
                                               float* __restrict__ vv) {
    __shared__ float su[4][128], sv[4][128];
    const int t = threadIdx.x;
    const int j = t & 127, q = t >> 7;
    float u = 0.0f, v = 0.0f;
    if (j < HID) {
        #pragma unroll 8
        for (int d = q * 128; d < q * 128 + 128; ++d) {
            const float wv = W1[d * HID + j];
            u = fmaf(beta[d], wv, u);
            v = fmaf(gamma[d], wv, v);
        }
    }
    su[q][j] = u; sv[q][j] = v;
    __syncthreads();
    if (q == 0) {
        ub[j] = su[0][j] + su[1][j] + su[2][j] + su[3][j] +
                ((j < HID) ? b1[j] : 0.0f);
        vv[j] = sv[0][j] + sv[1][j] + sv[2][j] + sv[3][j];
    }
}

// ------- scorer: raw-x MFMA + LN-as-epilogue, triple-buffered counted-vmcnt fc1 -------
__global__ __launch_bounds__(256) void scorer_k(const float* __restrict__ x,
                                                const unsigned short* __restrict__ W1f,
                                                const unsigned short* __restrict__ W2f,
                                                const float* __restrict__ ub,
                                                const float* __restrict__ vv,
                                                const float* __restrict__ b2,
                                                const float* __restrict__ scale,
                                                float* __restrict__ logits,
                                                float* __restrict__ pm,
                                                float* __restrict__ psum) {
    __shared__ char bsm[3][8192];       // B triple buffer (8 KB K-chunk each)
    __shared__ char hsm[4][4096];       // per-wave h bounce
    const int tid = threadIdx.x;
    const int lane = tid & 63;
    const int w = tid >> 6;
    const int l15 = lane & 15;
    const int hi = lane >> 4;
    const int tile = blockIdx.x * 4 + w;
    const int wt0 = tile * 16;
    char* hb = &hsm[w][0];

    // stage fc1 chunk 0 ASAP (hides under the LN pass)
    {
        const unsigned short* s0 = W1f + w * 1024 + lane * 8;
        gload_lds16(s0, &bsm[0][w * 2048]);
        gload_lds16(s0 + 512, &bsm[0][w * 2048 + 1024]);
    }

    // ---- LN stats: full-row sums, 2-shfl reduce (4 lanes share a row) ----
    const float* xrow = x + (size_t)(wt0 + l15) * DIM + hi * 8;
    float s = 0.0f, ss = 0.0f;
    #pragma unroll
    for (int kc = 0; kc < 16; ++kc) {
        const f32x4 a = *(const f32x4*)(xrow + kc * 32);
        const f32x4 b = *(const f32x4*)(xrow + kc * 32 + 4);
        s += a.x + a.y + a.z + a.w + b.x + b.y + b.z + b.w;
        ss += a.x * a.x + a.y * a.y + a.z * a.z + a.w * a.w +
              b.x * b.x + b.y * b.y + b.z * b.z + b.w * b.w;
        if ((kc & 3) == 3) __builtin_amdgcn_sched_barrier(0);
    }
    s += __shfl_xor(s, 16); ss += __shfl_xor(ss, 16);
    s += __shfl_xor(s, 32); ss += __shfl_xor(ss, 32);
    const float mu = s * (1.0f / 512.0f);
    const float inv = rsqrtf(ss * (1.0f / 512.0f) - mu * mu + LN_EPS);

    asm volatile("" : "+v"(xrow));   // launder: stop CSE keeping pass-1 values alive

    // ---- fc1: 16 K-steps, A = raw x (bf16 cast, 1-step reg prefetch),
    //      B triple-buffered via DMA, 1 barrier/step, counted vmcnt ----
    f32x4 acc[8] = {};
    f32x4 xa = *(const f32x4*)(xrow);           // kc=0 frag (L2-hot)
    f32x4 xb = *(const f32x4*)(xrow + 4);
    #pragma unroll
    for (int kc = 0; kc < 16; ++kc) {
        f32x4 xa_n, xb_n;
        if (kc < 15) {   // stage next B chunk + prefetch next x frag
            const unsigned short* sn = W1f + (kc + 1) * 4096 + w * 1024 + lane * 8;
            gload_lds16(sn, &bsm[(kc + 1) % 3][w * 2048]);
            gload_lds16(sn + 512, &bsm[(kc + 1) % 3][w * 2048 + 1024]);
            xa_n = *(const f32x4*)(xrow + (kc + 1) * 32);
            xb_n = *(const f32x4*)(xrow + (kc + 1) * 32 + 4);
            // 4 newest in flight (2 DMA + 2 x-loads); drain DMA(kc) + xf(kc)
            asm volatile("s_waitcnt vmcnt(4)" ::: "memory");
        } else {
            asm volatile("s_waitcnt vmcnt(0)" ::: "memory");
        }
        __builtin_amdgcn_sched_barrier(0);
        __builtin_amdgcn_s_barrier();      // all waves' stage(kc) landed
        short8 af;
        af[0] = (short)f2bf(xa.x); af[1] = (short)f2bf(xa.y);
        af[2] = (short)f2bf(xa.z); af[3] = (short)f2bf(xa.w);
        af[4] = (short)f2bf(xb.x); af[5] = (short)f2bf(xb.y);
        af[6] = (short)f2bf(xb.z); af[7] = (short)f2bf(xb.w);
        const char* bb = &bsm[kc % 3][lane * 16];
        __builtin_amdgcn_s_setprio(1);
        #pragma unroll
        for (int jj = 0; jj < 8; ++jj) {
            const short8 bf = *(const short8*)(bb + jj * 1024);
            acc[jj] = __builtin_amdgcn_mfma_f32_16x16x32_bf16(af, bf, acc[jj], 0, 0, 0);
        }
        __builtin_amdgcn_s_setprio(0);
        xa = xa_n; xb = xb_n;
    }

    // ---- LN epilogue + bias + GELU -> wave-private LDS (swizzled bf16) ----
    // h[t][j] = inv_t*acc - mu_t*inv_t*vv[j] + ub[j]
    float invr[4], muir[4];
    #pragma unroll
    for (int r = 0; r < 4; ++r) {
        const int tk = 4 * hi + r;
        const float m_ = __shfl(mu, tk);
        const float i_ = __shfl(inv, tk);
        invr[r] = i_;
        muir[r] = m_ * i_;
    }
    #pragma unroll
    for (int jj = 0; jj < 8; ++jj) {
        const int col = jj * 16 + l15;
        const float ubj = ub[col];
        const float vvj = vv[col];
        #pragma unroll
        for (int reg = 0; reg < 4; ++reg) {
            const int t = 4 * hi + reg;
            const float pre = fmaf(invr[reg], acc[jj][reg],
                                   fmaf(-muir[reg], vvj, ubj));
            const float g = 0.5f * pre * (1.0f + erff(pre * 0.70710678118f));
            *(unsigned short*)(hb + t * 256 + ((col * 2) ^ ((t & 7) << 4))) = f2bf(g);
        }
    }
    asm volatile("s_waitcnt lgkmcnt(0)" ::: "memory");
    __builtin_amdgcn_sched_barrier(0);

    // ---- fc2: 16 tokens x 64 k (per-wave, W2f from L2) ----
    f32x4 acc2[4] = {};
    {
        const unsigned short* w2 = W2f + lane * 8;
        #pragma unroll
        for (int kc = 0; kc < 4; ++kc) {
            const short8 a2 = *(const short8*)(hb + l15 * 256 +
                                               ((kc * 64 + hi * 16) ^ ((l15 & 7) << 4)));
            __builtin_amdgcn_s_setprio(1);
            #pragma unroll
            for (int nt = 0; nt < 4; ++nt) {
                const short8 bfr = *(const short8*)(w2 + (size_t)(nt * 4 + kc) * 512);
                acc2[nt] = __builtin_amdgcn_mfma_f32_16x16x32_bf16(a2, bfr, acc2[nt], 0, 0, 0);
            }
            __builtin_amdgcn_s_setprio(0);
        }
    }

    // ---- logits store (16B/lane contiguous) + per-tile softmax partials ----
    const float sc = scale[0];
    #pragma unroll
    for (int nt = 0; nt < 4; ++nt) {
        const int k = nt * 16 + l15;
        const float bb = b2[k];
        f32x4 lv;
        lv.x = (acc2[nt][0] + bb) * sc;
        lv.y = (acc2[nt][1] + bb) * sc;
        lv.z = (acc2[nt][2] + bb) * sc;
        lv.w = (acc2[nt][3] + bb) * sc;
        *(f32x4*)(logits + (size_t)k * N_TOK + wt0 + hi * 4) = lv;
        float m4 = fmaxf(fmaxf(lv.x, lv.y), fmaxf(lv.z, lv.w));
        float s4 = __expf(lv.x - m4) + __expf(lv.y - m4) +
                   __expf(lv.z - m4) + __expf(lv.w - m4);
        #pragma unroll
        for (int o = 16; o <= 32; o <<= 1) {
            const float om = __shfl_xor(m4, o);
            const float os = __shfl_xor(s4, o);
            const float nm = fmaxf(m4, om);
            s4 = s4 * __expf(m4 - nm) + os * __expf(om - nm);
            m4 = nm;
        }
        if (hi == 0) {
            pm[tile * 64 + k] = m4;
            psum[tile * 64 + k] = s4;
        }
    }
}

// ---------------- stats: combine per-tile partials ----------------
__global__ __launch_bounds__(256) void stats_k(const float* __restrict__ pm,
                                               const float* __restrict__ psum,
                                               float* __restrict__ smax,
                                               float* __restrict__ sinv) {
    const int k = blockIdx.x;
    const int tid = threadIdx.x;
    __shared__ float rm[4], rs[4];
    float m = -1e30f, s = 0.0f;
    for (int b = tid; b < NTILE; b += 256) {
        const float pmv = pm[b * 64 + k];
        const float psv = psum[b * 64 + k];
        const float nm = fmaxf(m, pmv);
        s = s * __expf(m - nm) + psv * __expf(pmv - nm);
        m = nm;
    }
    #pragma unroll
    for (int o = 32; o >= 1; o >>= 1) {
        const float om = __shfl_xor(m, o);
        const float os = __shfl_xor(s, o);
        const float nm = fmaxf(m, om);
        s = s * __expf(m - nm) + os * __expf(om - nm);
        m = nm;
    }
    if ((tid & 63) == 0) { rm[tid >> 6] = m; rs[tid >> 6] = s; }
    __syncthreads();
    if (tid == 0) {
        float fm = rm[0], fs = rs[0];
        for (int i = 1; i < 4; ++i) {
            const float nm = fmaxf(fm, rm[i]);
            fs = fs * __expf(fm - nm) + rs[i] * __expf(rm[i] - nm);
            fm = nm;
        }
        smax[k] = fm;
        sinv[k] = 1.0f / fs;
    }
}

// ---------------- agg: partial[tb][k][d], 512 tokens/block (R3-proven) ----------------
__global__ __launch_bounds__(512, 4) void agg_k(const float* __restrict__ x,
                                                const float* __restrict__ logits,
                                                const float* __restrict__ smax,
                                                const float* __restrict__ sinv,
                                                float* __restrict__ part) {
    __shared__ float ps[64][65];
    const int tid = threadIdx.x;
    const int dg = blockIdx.y;
    const int tb = blockIdx.x;
    const int kq = tid >> 5;            // 0..15 -> k = kq*4..+4
    const int dt = tid & 31;
    const int dbase = dg * 128 + dt * 4;
    const int n_start = tb * 512;
    const int sk = tid >> 3;            // staging: k row 0..63
    const int np = (tid & 7) * 8;       // staging: 8 tokens
    const float mk = smax[sk];
    const float ik = sinv[sk];
    float acc[4][4] = {};

    for (int c = 0; c < 8; ++c) {
        const int n0 = n_start + c * 64;
        const f32x4 va = *(const f32x4*)&logits[(size_t)sk * N_TOK + n0 + np];
        const f32x4 vb = *(const f32x4*)&logits[(size_t)sk * N_TOK + n0 + np + 4];
        __syncthreads();
        ps[sk][np + 0] = __expf(va.x - mk) * ik;
        ps[sk][np + 1] = __expf(va.y - mk) * ik;
        ps[sk][np + 2] = __expf(va.z - mk) * ik;
        ps[sk][np + 3] = __expf(va.w - mk) * ik;
        ps[sk][np + 4] = __expf(vb.x - mk) * ik;
        ps[sk][np + 5] = __expf(vb.y - mk) * ik;
        ps[sk][np + 6] = __expf(vb.z - mk) * ik;
        ps[sk][np + 7] = __expf(vb.w - mk) * ik;
        __syncthreads();
        #pragma unroll 4
        for (int n = 0; n < 64; ++n) {
            const f32x4 xv = *(const f32x4*)&x[(size_t)(n0 + n) * DIM + dbase];
            #pragma unroll
            for (int i = 0; i < 4; ++i) {
                const float p = ps[kq * 4 + i][n];
                acc[i][0] = fmaf(p, xv.x, acc[i][0]);
                acc[i][1] = fmaf(p, xv.y, acc[i][1]);
                acc[i][2] = fmaf(p, xv.z, acc[i][2]);
                acc[i][3] = fmaf(p, xv.w, acc[i][3]);
            }
        }
    }
    #pragma unroll
    for (int i = 0; i < 4; ++i) {
        const int k = kq * 4 + i;
        f32x4 v;
        v.x = acc[i][0]; v.y = acc[i][1]; v.z = acc[i][2]; v.w = acc[i][3];
        *(f32x4*)&part[((size_t)tb * 64 + k) * 512 + dbase] = v;
    }
}

// ---------------- reduce: out[k][d] = sum_tb part[tb][k][d] ----------------
__global__ __launch_bounds__(256) void reduce_k(const float* __restrict__ part,
                                                float* __restrict__ out) {
    const int idx = blockIdx.x * 256 + threadIdx.x;  // 0..32767
    const int k = idx >> 9, d = idx & 511;
    float s = 0.0f;
    for (int tb = 0; tb < 128; ++tb) s += part[((size_t)tb * 64 + k) * 512 + d];
    out[idx] = s;
}

extern "C" void kernel_launch(void* const* d_in, const int* in_sizes, int n_in,
                              void* d_out, int out_size, void* d_ws, size_t ws_size,
                              hipStream_t stream) {
    const float* x     = (const float*)d_in[0];
    const float* gamma = (const float*)d_in[1];
    const float* beta  = (const float*)d_in[2];
    const float* W1    = (const float*)d_in[3];
    const float* b1    = (const float*)d_in[4];
    const float* W2    = (const float*)d_in[5];
    const float* b2    = (const float*)d_in[6];
    const float* scale = (const float*)d_in[7];
    float* out = (float*)d_out;
    float* ws  = (float*)d_ws;

    float* logits = ws + WS_LOGITS;
    float* part   = ws + WS_PART;
    float* pm     = ws + WS_PM;
    float* psum   = ws + WS_PS;
    unsigned short* W1f = (unsigned short*)(ws + WS_W1F);
    unsigned short* W2f = (unsigned short*)(ws + WS_W2F);
    float* ubv  = ws + WS_UB;
    float* vvv  = ws + WS_VV;
    float* smax = ws + WS_SMAX;
    float* sinv = ws + WS_SINV;

    hipLaunchKernelGGL(prep_k, dim3(256), dim3(256), 0, stream,
                       W1, gamma, W2, W1f, W2f);
    hipLaunchKernelGGL(prep2_k, dim3(1), dim3(512), 0, stream,
                       W1, b1, gamma, beta, ubv, vvv);
    hipLaunchKernelGGL(scorer_k, dim3(NTILE / 4), dim3(256), 0, stream,
                       x, W1f, W2f, ubv, vvv, b2, scale, logits, pm, psum);
    hipLaunchKernelGGL(stats_k, dim3(KTOK), dim3(256), 0, stream,
                       pm, psum, smax, sinv);
    hipLaunchKernelGGL(agg_k, dim3(128, 4), dim3(512), 0, stream,
                       x, logits, smax, sinv, part);
    hipLaunchKernelGGL(reduce_k, dim3(128), dim3(256), 0, stream,
                       part, out);
}

// Round 10
// 156.629 us; speedup vs baseline: 1.2537x; 1.0767x over previous
//
#include <hip/hip_runtime.h>
#include <math.h>

#define N_TOK 65536
#define DIM   512
#define HID   102
#define KTOK  64
#define NTILE 4096          // 16-token tiles (one per wave)
#define LN_EPS 1e-5f

typedef __attribute__((ext_vector_type(8))) short short8;
typedef __attribute__((ext_vector_type(4))) float f32x4;

// ws layout (float offsets)
#define WS_LOGITS 0u
#define WS_PART   4194304u                 // 128*64*512
#define WS_PM     (WS_PART + 4194304u)     // 4096*64
#define WS_PS     (WS_PM + 262144u)        // 4096*64
#define WS_W1F    (WS_PS + 262144u)        // 65536 ushort (chunk-packed frags, gamma-folded)
#define WS_W2F    (WS_W1F + 32768u)        // 8192 ushort (packed frags)
#define WS_UB     (WS_W2F + 4096u)         // 128: sum(beta*W1)+b1
#define WS_VV     (WS_UB + 128u)           // 128: sum(gamma*W1)
#define WS_SMAX   (WS_VV + 128u)
#define WS_SINV   (WS_SMAX + 64u)

__device__ __forceinline__ unsigned short f2bf(float f) {
    unsigned int u = __float_as_uint(f);
    unsigned int r = (u + 0x7fffu + ((u >> 16) & 1u)) >> 16;
    return (unsigned short)r;
}

__device__ __forceinline__ void gload_lds16(const void* g, void* l) {
    __builtin_amdgcn_global_load_lds(
        (const __attribute__((address_space(1))) unsigned int*)g,
        (__attribute__((address_space(3))) unsigned int*)l, 16, 0, 0);
}

// ---------------- prep: weights packed in MFMA-fragment order ----------------
// W1f chunk-packed, GAMMA-FOLDED: W1f[kc*4096 + jj*512 + lane*8 + e] =
//   bf16(gamma[d]*W1[d][j]), j=jj*16+(lane&15), d=kc*32+(lane>>4)*8+e
// W2f[((N*4+kc)*64+lane)*8+e] = W2[j][k], k=N*16+(lane&15), j=kc*32+(lane>>4)*8+e
__global__ __launch_bounds__(256) void prep_k(const float* __restrict__ W1,
                                              const float* __restrict__ gamma,
                                              const float* __restrict__ W2,
                                              unsigned short* __restrict__ W1f,
                                              unsigned short* __restrict__ W2f) {
    const int idx = blockIdx.x * 256 + threadIdx.x;   // 0..65535
    {
        const int e = idx & 7, lane = (idx >> 3) & 63;
        const int jj = (idx >> 9) & 7, kc = (idx >> 12) & 15;
        const int j = jj * 16 + (lane & 15);
        const int d = kc * 32 + (lane >> 4) * 8 + e;
        W1f[idx] = (j < HID) ? f2bf(gamma[d] * W1[d * HID + j]) : (unsigned short)0;
    }
    if (idx < 8192) {
        const int e = idx & 7, lane = (idx >> 3) & 63;
        const int kc = (idx >> 9) & 3, N = (idx >> 11) & 3;
        const int j = kc * 32 + (lane >> 4) * 8 + e;
        const int k = N * 16 + (lane & 15);
        W2f[idx] = (j < HID) ? f2bf(W2[j * KTOK + k]) : (unsigned short)0;
    }
}

// ---------------- prep2: ub[j]=sum_d beta*W1 + b1, vv[j]=sum_d gamma*W1 ----------------
__global__ __launch_bounds__(512) void prep2_k(const float* __restrict__ W1,
                                               const float* __restrict__ b1,
                                               const float* __restrict__ gamma,
                                               const float* __restrict__ beta,
                                               float* __restrict__ ub,
                                               float* __restrict__ vv) {
    __shared__ float su[4][128], sv[4][128];
    const int t = threadIdx.x;
    const int j = t & 127, q = t >> 7;
    float u = 0.0f, v = 0.0f;
    if (j < HID) {
        #pragma unroll 8
        for (int d = q * 128; d < q * 128 + 128; ++d) {
            const float wv = W1[d * HID + j];
            u = fmaf(beta[d], wv, u);
            v = fmaf(gamma[d], wv, v);
        }
    }
    su[q][j] = u; sv[q][j] = v;
    __syncthreads();
    if (q == 0) {
        ub[j] = su[0][j] + su[1][j] + su[2][j] + su[3][j] +
                ((j < HID) ? b1[j] : 0.0f);
        vv[j] = sv[0][j] + sv[1][j] + sv[2][j] + sv[3][j];
    }
}

// ------- scorer: 128 tokens/block (8 waves), raw-x MFMA + LN epilogue,
//         depth-2 counted-vmcnt DMA pipeline, 4 LDS buffers, h aliased -------
__global__ __launch_bounds__(512) void scorer_k(const float* __restrict__ x,
                                                const unsigned short* __restrict__ W1f,
                                                const unsigned short* __restrict__ W2f,
                                                const float* __restrict__ ub,
                                                const float* __restrict__ vv,
                                                const float* __restrict__ b2,
                                                const float* __restrict__ scale,
                                                float* __restrict__ logits,
                                                float* __restrict__ pm,
                                                float* __restrict__ psum) {
    __shared__ char smem[4 * 8192];     // 4 B-buffers; post-fc1 aliased as h[8][4096]
    const int tid = threadIdx.x;
    const int lane = tid & 63;
    const int w = tid >> 6;             // wave 0..7
    const int l15 = lane & 15;
    const int hi = lane >> 4;
    const int tile = blockIdx.x * 8 + w;
    const int wt0 = tile * 16;
    char* hb = smem + w * 4096;         // valid only after fc1 + barrier

    // prologue: stage chunks 0,1 (1 KB per wave each) — hides under LN
    gload_lds16(W1f + w * 512 + lane * 8, smem + w * 1024);
    gload_lds16(W1f + 4096 + w * 512 + lane * 8, smem + 8192 + w * 1024);

    // ---- LN stats: full-row sums, 2-shfl reduce (4 lanes share a row) ----
    const float* xrow = x + (size_t)(wt0 + l15) * DIM + hi * 8;
    float s = 0.0f, ss = 0.0f;
    #pragma unroll
    for (int kc = 0; kc < 16; ++kc) {
        const f32x4 a = *(const f32x4*)(xrow + kc * 32);
        const f32x4 b = *(const f32x4*)(xrow + kc * 32 + 4);
        s += a.x + a.y + a.z + a.w + b.x + b.y + b.z + b.w;
        ss += a.x * a.x + a.y * a.y + a.z * a.z + a.w * a.w +
              b.x * b.x + b.y * b.y + b.z * b.z + b.w * b.w;
        if ((kc & 7) == 7) __builtin_amdgcn_sched_barrier(0);
    }
    s += __shfl_xor(s, 16); ss += __shfl_xor(ss, 16);
    s += __shfl_xor(s, 32); ss += __shfl_xor(ss, 32);
    const float mu = s * (1.0f / 512.0f);
    const float inv = rsqrtf(ss * (1.0f / 512.0f) - mu * mu + LN_EPS);

    asm volatile("" : "+v"(xrow));   // launder: stop CSE keeping pass-1 values alive

    // ---- fc1: 16 K-steps, A = raw x (bf16 cast), depth-2 DMA pipeline ----
    f32x4 acc[8] = {};
    f32x4 xa = *(const f32x4*)(xrow);           // xload(0), L2-hot
    f32x4 xb = *(const f32x4*)(xrow + 4);
    #pragma unroll
    for (int kc = 0; kc < 16; ++kc) {
        f32x4 xa_n, xb_n;
        if (kc < 15) {                           // xload(kc+1)
            xa_n = *(const f32x4*)(xrow + (kc + 1) * 32);
            xb_n = *(const f32x4*)(xrow + (kc + 1) * 32 + 4);
        }
        if (kc < 14) {                           // DMA stage(kc+2)
            gload_lds16(W1f + (kc + 2) * 4096 + w * 512 + lane * 8,
                        smem + ((kc + 2) & 3) * 8192 + w * 1024);
        }
        // queue (oldest->new): xload(kc)2, DMA(kc+1)1, xload(kc+1)2, DMA(kc+2)1
        if (kc == 0 || kc == 14)
            asm volatile("s_waitcnt vmcnt(3)" ::: "memory");
        else if (kc < 14)
            asm volatile("s_waitcnt vmcnt(4)" ::: "memory");
        else
            asm volatile("s_waitcnt vmcnt(0)" ::: "memory");
        __builtin_amdgcn_sched_barrier(0);
        __builtin_amdgcn_s_barrier();            // all waves' stage(kc) landed
        short8 af;
        af[0] = (short)f2bf(xa.x); af[1] = (short)f2bf(xa.y);
        af[2] = (short)f2bf(xa.z); af[3] = (short)f2bf(xa.w);
        af[4] = (short)f2bf(xb.x); af[5] = (short)f2bf(xb.y);
        af[6] = (short)f2bf(xb.z); af[7] = (short)f2bf(xb.w);
        const char* bb = smem + (kc & 3) * 8192 + lane * 16;
        __builtin_amdgcn_s_setprio(1);
        #pragma unroll
        for (int jj = 0; jj < 8; ++jj) {
            const short8 bf = *(const short8*)(bb + jj * 1024);
            acc[jj] = __builtin_amdgcn_mfma_f32_16x16x32_bf16(af, bf, acc[jj], 0, 0, 0);
        }
        __builtin_amdgcn_s_setprio(0);
        xa = xa_n; xb = xb_n;
    }
    __syncthreads();   // all waves done with B buffers -> smem becomes h space

    // ---- LN epilogue + bias + GELU -> wave-private LDS (swizzled bf16) ----
    // h[t][j] = inv_t*acc - mu_t*inv_t*vv[j] + ub[j]
    float invr[4], muir[4];
    #pragma unroll
    for (int r = 0; r < 4; ++r) {
        const int tk = 4 * hi + r;
        const float m_ = __shfl(mu, tk);
        const float i_ = __shfl(inv, tk);
        invr[r] = i_;
        muir[r] = m_ * i_;
    }
    #pragma unroll
    for (int jj = 0; jj < 8; ++jj) {
        const int col = jj * 16 + l15;
        const float ubj = ub[col];
        const float vvj = vv[col];
        #pragma unroll
        for (int reg = 0; reg < 4; ++reg) {
            const int t = 4 * hi + reg;
            const float pre = fmaf(invr[reg], acc[jj][reg],
                                   fmaf(-muir[reg], vvj, ubj));
            const float g = 0.5f * pre * (1.0f + erff(pre * 0.70710678118f));
            *(unsigned short*)(hb + t * 256 + ((col * 2) ^ ((t & 7) << 4))) = f2bf(g);
        }
    }
    asm volatile("s_waitcnt lgkmcnt(0)" ::: "memory");
    __builtin_amdgcn_sched_barrier(0);

    // ---- fc2: 16 tokens x 64 k (per-wave, W2f from L2) ----
    f32x4 acc2[4] = {};
    {
        const unsigned short* w2 = W2f + lane * 8;
        #pragma unroll
        for (int kc = 0; kc < 4; ++kc) {
            const short8 a2 = *(const short8*)(hb + l15 * 256 +
                                               ((kc * 64 + hi * 16) ^ ((l15 & 7) << 4)));
            __builtin_amdgcn_s_setprio(1);
            #pragma unroll
            for (int nt = 0; nt < 4; ++nt) {
                const short8 bfr = *(const short8*)(w2 + (size_t)(nt * 4 + kc) * 512);
                acc2[nt] = __builtin_amdgcn_mfma_f32_16x16x32_bf16(a2, bfr, acc2[nt], 0, 0, 0);
            }
            __builtin_amdgcn_s_setprio(0);
        }
    }

    // ---- logits store (16B/lane contiguous) + per-tile softmax partials ----
    const float sc = scale[0];
    #pragma unroll
    for (int nt = 0; nt < 4; ++nt) {
        const int k = nt * 16 + l15;
        const float bb = b2[k];
        f32x4 lv;
        lv.x = (acc2[nt][0] + bb) * sc;
        lv.y = (acc2[nt][1] + bb) * sc;
        lv.z = (acc2[nt][2] + bb) * sc;
        lv.w = (acc2[nt][3] + bb) * sc;
        *(f32x4*)(logits + (size_t)k * N_TOK + wt0 + hi * 4) = lv;
        float m4 = fmaxf(fmaxf(lv.x, lv.y), fmaxf(lv.z, lv.w));
        float s4 = __expf(lv.x - m4) + __expf(lv.y - m4) +
                   __expf(lv.z - m4) + __expf(lv.w - m4);
        #pragma unroll
        for (int o = 16; o <= 32; o <<= 1) {
            const float om = __shfl_xor(m4, o);
            const float os = __shfl_xor(s4, o);
            const float nm = fmaxf(m4, om);
            s4 = s4 * __expf(m4 - nm) + os * __expf(om - nm);
            m4 = nm;
        }
        if (hi == 0) {
            pm[tile * 64 + k] = m4;
            psum[tile * 64 + k] = s4;
        }
    }
}

// ---------------- stats: combine per-tile partials ----------------
__global__ __launch_bounds__(256) void stats_k(const float* __restrict__ pm,
                                               const float* __restrict__ psum,
                                               float* __restrict__ smax,
                                               float* __restrict__ sinv) {
    const int k = blockIdx.x;
    const int tid = threadIdx.x;
    __shared__ float rm[4], rs[4];
    float m = -1e30f, s = 0.0f;
    for (int b = tid; b < NTILE; b += 256) {
        const float pmv = pm[b * 64 + k];
        const float psv = psum[b * 64 + k];
        const float nm = fmaxf(m, pmv);
        s = s * __expf(m - nm) + psv * __expf(pmv - nm);
        m = nm;
    }
    #pragma unroll
    for (int o = 32; o >= 1; o >>= 1) {
        const float om = __shfl_xor(m, o);
        const float os = __shfl_xor(s, o);
        const float nm = fmaxf(m, om);
        s = s * __expf(m - nm) + os * __expf(om - nm);
        m = nm;
    }
    if ((tid & 63) == 0) { rm[tid >> 6] = m; rs[tid >> 6] = s; }
    __syncthreads();
    if (tid == 0) {
        float fm = rm[0], fs = rs[0];
        for (int i = 1; i < 4; ++i) {
            const float nm = fmaxf(fm, rm[i]);
            fs = fs * __expf(fm - nm) + rs[i] * __expf(rm[i] - nm);
            fm = nm;
        }
        smax[k] = fm;
        sinv[k] = 1.0f / fs;
    }
}

// ---------------- agg: partial[tb][k][d], 512 tokens/block (R3-proven) ----------------
__global__ __launch_bounds__(512, 4) void agg_k(const float* __restrict__ x,
                                                const float* __restrict__ logits,
                                                const float* __restrict__ smax,
                                                const float* __restrict__ sinv,
                                                float* __restrict__ part) {
    __shared__ float ps[64][65];
    const int tid = threadIdx.x;
    const int dg = blockIdx.y;
    const int tb = blockIdx.x;
    const int kq = tid >> 5;            // 0..15 -> k = kq*4..+4
    const int dt = tid & 31;
    const int dbase = dg * 128 + dt * 4;
    const int n_start = tb * 512;
    const int sk = tid >> 3;            // staging: k row 0..63
    const int np = (tid & 7) * 8;       // staging: 8 tokens
    const float mk = smax[sk];
    const float ik = sinv[sk];
    float acc[4][4] = {};

    for (int c = 0; c < 8; ++c) {
        const int n0 = n_start + c * 64;
        const f32x4 va = *(const f32x4*)&logits[(size_t)sk * N_TOK + n0 + np];
        const f32x4 vb = *(const f32x4*)&logits[(size_t)sk * N_TOK + n0 + np + 4];
        __syncthreads();
        ps[sk][np + 0] = __expf(va.x - mk) * ik;
        ps[sk][np + 1] = __expf(va.y - mk) * ik;
        ps[sk][np + 2] = __expf(va.z - mk) * ik;
        ps[sk][np + 3] = __expf(va.w - mk) * ik;
        ps[sk][np + 4] = __expf(vb.x - mk) * ik;
        ps[sk][np + 5] = __expf(vb.y - mk) * ik;
        ps[sk][np + 6] = __expf(vb.z - mk) * ik;
        ps[sk][np + 7] = __expf(vb.w - mk) * ik;
        __syncthreads();
        #pragma unroll 4
        for (int n = 0; n < 64; ++n) {
            const f32x4 xv = *(const f32x4*)&x[(size_t)(n0 + n) * DIM + dbase];
            #pragma unroll
            for (int i = 0; i < 4; ++i) {
                const float p = ps[kq * 4 + i][n];
                acc[i][0] = fmaf(p, xv.x, acc[i][0]);
                acc[i][1] = fmaf(p, xv.y, acc[i][1]);
                acc[i][2] = fmaf(p, xv.z, acc[i][2]);
                acc[i][3] = fmaf(p, xv.w, acc[i][3]);
            }
        }
    }
    #pragma unroll
    for (int i = 0; i < 4; ++i) {
        const int k = kq * 4 + i;
        f32x4 v;
        v.x = acc[i][0]; v.y = acc[i][1]; v.z = acc[i][2]; v.w = acc[i][3];
        *(f32x4*)&part[((size_t)tb * 64 + k) * 512 + dbase] = v;
    }
}

// ---------------- reduce: out[k][d] = sum_tb part[tb][k][d] ----------------
__global__ __launch_bounds__(256) void reduce_k(const float* __restrict__ part,
                                                float* __restrict__ out) {
    const int idx = blockIdx.x * 256 + threadIdx.x;  // 0..32767
    const int k = idx >> 9, d = idx & 511;
    float s = 0.0f;
    for (int tb = 0; tb < 128; ++tb) s += part[((size_t)tb * 64 + k) * 512 + d];
    out[idx] = s;
}

extern "C" void kernel_launch(void* const* d_in, const int* in_sizes, int n_in,
                              void* d_out, int out_size, void* d_ws, size_t ws_size,
                              hipStream_t stream) {
    const float* x     = (const float*)d_in[0];
    const float* gamma = (const float*)d_in[1];
    const float* beta  = (const float*)d_in[2];
    const float* W1    = (const float*)d_in[3];
    const float* b1    = (const float*)d_in[4];
    const float* W2    = (const float*)d_in[5];
    const float* b2    = (const float*)d_in[6];
    const float* scale = (const float*)d_in[7];
    float* out = (float*)d_out;
    float* ws  = (float*)d_ws;

    float* logits = ws + WS_LOGITS;
    float* part   = ws + WS_PART;
    float* pm     = ws + WS_PM;
    float* psum   = ws + WS_PS;
    unsigned short* W1f = (unsigned short*)(ws + WS_W1F);
    unsigned short* W2f = (unsigned short*)(ws + WS_W2F);
    float* ubv  = ws + WS_UB;
    float* vvv  = ws + WS_VV;
    float* smax = ws + WS_SMAX;
    float* sinv = ws + WS_SINV;

    hipLaunchKernelGGL(prep_k, dim3(256), dim3(256), 0, stream,
                       W1, gamma, W2, W1f, W2f);
    hipLaunchKernelGGL(prep2_k, dim3(1), dim3(512), 0, stream,
                       W1, b1, gamma, beta, ubv, vvv);
    hipLaunchKernelGGL(scorer_k, dim3(NTILE / 8), dim3(512), 0, stream,
                       x, W1f, W2f, ubv, vvv, b2, scale, logits, pm, psum);
    hipLaunchKernelGGL(stats_k, dim3(KTOK), dim3(256), 0, stream,
                       pm, psum, smax, sinv);
    hipLaunchKernelGGL(agg_k, dim3(128, 4), dim3(512), 0, stream,
                       x, logits, smax, sinv, part);
    hipLaunchKernelGGL(reduce_k, dim3(128), dim3(256), 0, stream,
                       part, out);
}